// Round 1
// 128.404 us; speedup vs baseline: 1.2052x; 1.2052x over previous
//
#include <hip/hip_runtime.h>

#define L_LEN   16384
#define P_DIM   512
#define CHUNK   64
#define NCHUNK  256        // L_LEN / CHUNK

#define KDIM    1024       // 2*P, re/im interleaved: k = 2p (re), 2p+1 (im)
#define NDIM    512
#define BM      128
#define BN      128
#define BK      64

typedef __bf16 bf16_t;
typedef __bf16 bf16x8 __attribute__((ext_vector_type(8)));
typedef float  floatx4 __attribute__((ext_vector_type(4)));

// Per-channel discretization constants: a = exp(lambda*step), B = (a-1)/lambda
__device__ __forceinline__ void channel_consts(const float* __restrict__ Lam,
                                               const float* __restrict__ lstep,
                                               int p, float& ar, float& ai,
                                               float& br, float& bi) {
    float lr = -expf(Lam[2 * p + 0]);     // Re(lambda) < 0
    float li = Lam[2 * p + 1];            // Im(lambda)
    float s  = expf(lstep[p]);
    float er = expf(lr * s);
    ar = er * cosf(li * s);
    ai = er * sinf(li * s);
    float dr = ar - 1.0f, di = ai;
    float inv = 1.0f / (lr * lr + li * li);
    br = (dr * lr + di * li) * inv;
    bi = (di * lr - dr * li) * inv;
}

// Phase 1: per (chunk, channel) local scan (zero init), write end state.
// 256 blocks (one per CU), 64-step loop.
__global__ void __launch_bounds__(P_DIM) k_scan_ends(const float* __restrict__ u,
        const float* __restrict__ Lam, const float* __restrict__ lstep,
        float2* __restrict__ endv) {
    int p = threadIdx.x;
    int c = blockIdx.x;
    float ar, ai, br, bi;
    channel_consts(Lam, lstep, p, ar, ai, br, bi);
    float xr = 0.f, xi = 0.f;
    const float* up = u + (size_t)c * CHUNK * P_DIM + p;
    #pragma unroll 8
    for (int k = 0; k < CHUNK; ++k) {
        float uv = up[(size_t)k * P_DIM];
        float nr = ar * xr - ai * xi + br * uv;
        float ni = ar * xi + ai * xr + bi * uv;
        xr = nr; xi = ni;
    }
    endv[(size_t)c * P_DIM + p] = make_float2(xr, xi);
}

// Phase 2: carry scan over chunks, parallel Kogge-Stone.
// carry[c+1] = A*carry[c] + endv[c] with A constant per channel -> weighted
// prefix sum. Block = 4 channels x 256 chunks = 1024 threads; 128 blocks.
__global__ void __launch_bounds__(1024) k_carry(const float* __restrict__ Lam,
        const float* __restrict__ lstep, const float2* __restrict__ endv,
        float2* __restrict__ carry) {
    __shared__ float2 zl[4 * (NCHUNK + 2)];   // +2 pad: spread channels across banks
    int tid = threadIdx.x;
    int g = tid & 3;                  // channel slot within block
    int c = tid >> 2;                 // chunk index 0..255
    int p = blockIdx.x * 4 + g;
    int zi_base = g * (NCHUNK + 2);

    float lr = -expf(Lam[2 * p + 0]);
    float li = Lam[2 * p + 1];
    float s  = expf(lstep[p]);
    float t  = s * (float)CHUNK;
    float er = expf(lr * t);
    float Ar = er * cosf(li * t);     // A = a^CHUNK
    float Ai = er * sinf(li * t);

    float2 e = endv[(size_t)c * P_DIM + p];
    float zr = e.x, zi = e.y;
    zl[zi_base + c] = make_float2(zr, zi);
    __syncthreads();
    for (int st = 1; st < NCHUNK; st <<= 1) {
        float tr = 0.f, ti = 0.f;
        if (c >= st) { float2 v = zl[zi_base + c - st]; tr = v.x; ti = v.y; }
        __syncthreads();
        zr += Ar * tr - Ai * ti;
        zi += Ar * ti + Ai * tr;
        zl[zi_base + c] = make_float2(zr, zi);
        float nAr = Ar * Ar - Ai * Ai;   // A^(2s)
        float nAi = 2.f * Ar * Ai;
        Ar = nAr; Ai = nAi;
        __syncthreads();
    }
    float2 cv = make_float2(0.f, 0.f);
    if (c > 0) cv = zl[zi_base + c - 1];   // exclusive prefix = state entering chunk c
    carry[(size_t)c * P_DIM + p] = cv;
}

// Phase 3: recompute local scan with carry init; write A bf16 row-major
// [t][1024], k interleaved (re at 2p, im at 2p+1) -> one 4B store/step.
__global__ void __launch_bounds__(P_DIM) k_materialize(const float* __restrict__ u,
        const float* __restrict__ Lam, const float* __restrict__ lstep,
        const float2* __restrict__ carry, bf16_t* __restrict__ A) {
    int p = threadIdx.x;
    int c = blockIdx.x;
    float ar, ai, br, bi;
    channel_consts(Lam, lstep, p, ar, ai, br, bi);
    float2 x0 = carry[(size_t)c * P_DIM + p];
    float xr = x0.x, xi = x0.y;
    const float* up = u + (size_t)c * CHUNK * P_DIM + p;
    uint32_t* Ap = (uint32_t*)(A + (size_t)c * CHUNK * KDIM) + p;   // elem 2p = u32 slot p
    #pragma unroll 4
    for (int k = 0; k < CHUNK; ++k) {
        float uv = up[(size_t)k * P_DIM];
        float nr = ar * xr - ai * xi + br * uv;
        float ni = ar * xi + ai * xr + bi * uv;
        xr = nr; xi = ni;
        bf16_t hr = (bf16_t)xr, hi = (bf16_t)xi;
        uint32_t pk = (uint32_t)__builtin_bit_cast(unsigned short, hr)
                    | ((uint32_t)__builtin_bit_cast(unsigned short, hi) << 16);
        Ap[(size_t)k * (KDIM / 2)] = pk;
    }
}

// Pack B operand, interleaved K: Bt[j][2p] = V_re[j][p], Bt[j][2p+1] = -V_im[j][p].
__global__ void __launch_bounds__(256) k_bt(const float* __restrict__ Vre,
        const float* __restrict__ Vim, bf16_t* __restrict__ Bt) {
    int idx = blockIdx.x * 256 + threadIdx.x;   // 0 .. 512*512-1 == j*512+p
    bf16_t r = (bf16_t)Vre[idx];
    bf16_t m = (bf16_t)(-Vim[idx]);
    uint32_t pk = (uint32_t)__builtin_bit_cast(unsigned short, r)
                | ((uint32_t)__builtin_bit_cast(unsigned short, m) << 16);
    ((uint32_t*)Bt)[idx] = pk;
}

// GEMM: out[m][n] = sum_k A[m][k]*Bt[n][k], spike threshold epilogue.
// 128x128 block tile, 4 waves each 64x64 (4x4 of 16x16x32 bf16 MFMA), BK=64.
// Staging via global_load_lds width=16: LINEAR LDS dest (lane-ordered),
// INVERSE-swizzled global source, swizzled ds_read (rule-21-correct pair).
// LDS slot (row, sc) holds global chunk (row, sc ^ (row&7)).
__global__ void __launch_bounds__(256) k_gemm(const bf16_t* __restrict__ A,
        const bf16_t* __restrict__ Bt, float* __restrict__ out) {
    __shared__ uint4 As4[BM * BK * 2 / 16];   // 16 KB
    __shared__ uint4 Bs4[BN * BK * 2 / 16];   // 16 KB

    const int tid  = threadIdx.x;
    const int lane = tid & 63;
    const int w    = tid >> 6;
    const int m0   = blockIdx.x * BM;
    const int n0   = blockIdx.y * BN;
    const int wm   = (w >> 1) * 64;
    const int wn   = (w & 1) * 64;

    const int fr_m = lane & 15;   // M/N index within 16x16 for A/B operands
    const int fr_g = lane >> 4;   // k-group (quad) 0..3

    floatx4 acc[4][4];
    #pragma unroll
    for (int i = 0; i < 4; ++i)
        #pragma unroll
        for (int j = 0; j < 4; ++j) {
            floatx4 z = {0.f, 0.f, 0.f, 0.f};
            acc[i][j] = z;
        }

    const bf16_t* Asrc = A  + (size_t)m0 * KDIM;
    const bf16_t* Bsrc = Bt + (size_t)n0 * KDIM;

    // Hoisted per-thread staging addresses. q = linear LDS chunk slot;
    // source chunk col = (q&7) ^ (row&7) so that swizzled reads land right.
    const bf16_t* ga[4]; const bf16_t* gb[4];
    char* la[4]; char* lb[4];
    #pragma unroll
    for (int i = 0; i < 4; ++i) {
        int q   = i * 256 + tid;
        int row = q >> 3;
        int gc  = (q & 7) ^ (row & 7);
        ga[i] = Asrc + (size_t)row * KDIM + gc * 8;
        gb[i] = Bsrc + (size_t)row * KDIM + gc * 8;
        la[i] = (char*)As4 + (size_t)q * 16;
        lb[i] = (char*)Bs4 + (size_t)q * 16;
    }

    for (int kt = 0; kt < KDIM; kt += BK) {
        __syncthreads();   // prior reads of LDS done before overwrite
        #pragma unroll
        for (int i = 0; i < 4; ++i) {
            __builtin_amdgcn_global_load_lds(
                (const __attribute__((address_space(1))) void*)(ga[i] + kt),
                (__attribute__((address_space(3))) void*)la[i], 16, 0, 0);
            __builtin_amdgcn_global_load_lds(
                (const __attribute__((address_space(1))) void*)(gb[i] + kt),
                (__attribute__((address_space(3))) void*)lb[i], 16, 0, 0);
        }
        __syncthreads();   // drains vmcnt(0) then barrier: tile ready
        #pragma unroll
        for (int kk = 0; kk < BK; kk += 32) {
            bf16x8 af[4], bf[4];
            #pragma unroll
            for (int i = 0; i < 4; ++i) {
                int m  = wm + i * 16 + fr_m;
                int cc = (kk >> 3) + fr_g;
                int sc = cc ^ (m & 7);
                af[i] = *(const bf16x8*)((const bf16_t*)As4 + m * BK + sc * 8);
            }
            #pragma unroll
            for (int j = 0; j < 4; ++j) {
                int n  = wn + j * 16 + fr_m;
                int cc = (kk >> 3) + fr_g;
                int sc = cc ^ (n & 7);
                bf[j] = *(const bf16x8*)((const bf16_t*)Bs4 + n * BK + sc * 8);
            }
            #pragma unroll
            for (int i = 0; i < 4; ++i)
                #pragma unroll
                for (int j = 0; j < 4; ++j)
                    acc[i][j] = __builtin_amdgcn_mfma_f32_16x16x32_bf16(
                        af[i], bf[j], acc[i][j], 0, 0, 0);
        }
    }

    // Epilogue: C/D layout col=lane&15, row=(lane>>4)*4+reg (m89-verified).
    #pragma unroll
    for (int i = 0; i < 4; ++i)
        #pragma unroll
        for (int j = 0; j < 4; ++j)
            #pragma unroll
            for (int r = 0; r < 4; ++r) {
                int rr = wm + i * 16 + fr_g * 4 + r;
                int cl = wn + j * 16 + fr_m;
                float v = acc[i][j][r];
                out[(size_t)(m0 + rr) * NDIM + (n0 + cl)] = (v > 1.0f) ? 1.0f : 0.0f;
            }
}

extern "C" void kernel_launch(void* const* d_in, const int* in_sizes, int n_in,
                              void* d_out, int out_size, void* d_ws, size_t ws_size,
                              hipStream_t stream) {
    (void)in_sizes; (void)n_in; (void)out_size; (void)ws_size;
    const float* u     = (const float*)d_in[0];
    const float* Lam   = (const float*)d_in[1];
    const float* lstep = (const float*)d_in[2];
    const float* Vre   = (const float*)d_in[3];
    const float* Vim   = (const float*)d_in[4];
    float* out = (float*)d_out;

    char* ws = (char*)d_ws;
    const size_t endv_bytes  = (size_t)NCHUNK * P_DIM * sizeof(float2);   // 1 MB
    const size_t carry_bytes = endv_bytes;                                // 1 MB
    const size_t bt_bytes    = (size_t)NDIM * KDIM * sizeof(bf16_t);      // 1 MB
    float2* endv  = (float2*)(ws);
    float2* carry = (float2*)(ws + endv_bytes);
    bf16_t* Bt    = (bf16_t*)(ws + endv_bytes + carry_bytes);
    bf16_t* A     = (bf16_t*)(ws + endv_bytes + carry_bytes + bt_bytes);  // 32 MB

    hipLaunchKernelGGL(k_scan_ends, dim3(NCHUNK), dim3(P_DIM), 0, stream,
                       u, Lam, lstep, endv);
    hipLaunchKernelGGL(k_bt, dim3(NDIM * P_DIM / 256), dim3(256), 0, stream,
                       Vre, Vim, Bt);
    hipLaunchKernelGGL(k_carry, dim3(P_DIM / 4), dim3(1024), 0, stream,
                       Lam, lstep, endv, carry);
    hipLaunchKernelGGL(k_materialize, dim3(NCHUNK), dim3(P_DIM), 0, stream,
                       u, Lam, lstep, carry, A);
    hipLaunchKernelGGL(k_gemm, dim3(L_LEN / BM, NDIM / BN), dim3(256), 0, stream,
                       A, Bt, out);
}